// Round 1
// 697.815 us; speedup vs baseline: 1.1062x; 1.1062x over previous
//
#include <hip/hip_runtime.h>
#include <hip/hip_bf16.h>
#include <math.h>

#define N_NODES 100000
#define N_EDGES 1200000
#define EO      64
#define HID     256
#define NOUT    128
#define KP      224     // 193 padded to 7*32 for K-loop
#define TILE_R  64
#define HSTR    264     // h LDS stride (bf16 elems), padded vs 256
#define PCAP    1280    // staged perm entries per tile (mean ~768); global fallback past this

typedef __attribute__((ext_vector_type(8))) short bf16x8;
typedef __attribute__((ext_vector_type(4))) float f32x4;

__device__ __forceinline__ short f2bf(float x) {
    __hip_bfloat16 h = __float2bfloat16(x);
    return *reinterpret_cast<short*>(&h);
}

__device__ __forceinline__ f32x4 max4(f32x4 a, f32x4 b) {
    f32x4 r;
    r.x = fmaxf(a.x, b.x); r.y = fmaxf(a.y, b.y);
    r.z = fmaxf(a.z, b.z); r.w = fmaxf(a.w, b.w);
    return r;
}

// ---- weight transpose + bf16 convert: W1T[n][k] (k<193 else 0), W2T[n][k] ----
__global__ void prep_k(const float* __restrict__ W1, const float* __restrict__ W2,
                       short* __restrict__ W1T, short* __restrict__ W2T) {
    int i = blockIdx.x * 256 + threadIdx.x;
    if (i < HID * KP) {
        int n = i / KP, k = i - n * KP;
        W1T[i] = (k < 193) ? f2bf(W1[k * HID + n]) : (short)0;
    } else {
        int j = i - HID * KP;
        if (j < NOUT * HID) {
            int n = j / HID, k = j - n * HID;
            W2T[j] = f2bf(W2[k * NOUT + n]);
        }
    }
}

// ---- CSR build ----
__global__ void hist_k(const int* __restrict__ ei, unsigned* __restrict__ hist) {
    int e = blockIdx.x * 256 + threadIdx.x;
    if (e < N_EDGES) atomicAdd(&hist[ei[N_EDGES + e]], 1u);
}

__global__ void scan_part_k(unsigned* __restrict__ off, unsigned* __restrict__ bsum) {
    __shared__ unsigned s[256];
    int t = threadIdx.x, i = blockIdx.x * 256 + t;
    unsigned v = (i < N_NODES) ? off[i] : 0u;
    s[t] = v; __syncthreads();
    for (int d = 1; d < 256; d <<= 1) {
        unsigned x = (t >= d) ? s[t - d] : 0u; __syncthreads();
        s[t] += x; __syncthreads();
    }
    if (i < N_NODES) off[i] = s[t] - v;       // block-local exclusive
    if (t == 255) bsum[blockIdx.x] = s[255];
}

__global__ void scan_top_k(const unsigned* __restrict__ bsum, unsigned* __restrict__ boff, int nb) {
    __shared__ unsigned s[512];
    int t = threadIdx.x;
    unsigned v = (t < nb) ? bsum[t] : 0u;
    s[t] = v; __syncthreads();
    for (int d = 1; d < 512; d <<= 1) {
        unsigned x = (t >= d) ? s[t - d] : 0u; __syncthreads();
        s[t] += x; __syncthreads();
    }
    boff[t] = s[t] - v;
}

__global__ void scan_add_k(unsigned* __restrict__ off, const unsigned* __restrict__ boff,
                           unsigned* __restrict__ cursor) {
    int i = blockIdx.x * 256 + threadIdx.x;
    if (i < N_NODES) {
        unsigned o = off[i] + boff[blockIdx.x];
        off[i] = o; cursor[i] = o;
    }
}

__global__ void place_k(const int* __restrict__ ei, unsigned* __restrict__ cursor,
                        unsigned* __restrict__ perm) {
    int e = blockIdx.x * 256 + threadIdx.x;
    if (e < N_EDGES) {
        int c = ei[N_EDGES + e];
        unsigned p = atomicAdd(&cursor[c], 1u);
        perm[p] = (unsigned)e;
    }
}

// ---- fused gather + MLP (bf16 MFMA, fp32 accum) ----
// Gather restructure vs previous version: the per-node dependent chain
// off[n] -> perm[p] -> ea[row] (3 global latencies, serial over 16 nodes/wave)
// is collapsed by staging off[65], u[batch[n]] and the tile's contiguous perm
// slice into LDS with coalesced loads. ea addresses then come from LDS and the
// 256B ea loads pipeline across node iterations.
__launch_bounds__(256)
__global__ void fused_k(const unsigned* __restrict__ off, const unsigned* __restrict__ perm,
                        const float* __restrict__ ea, const float* __restrict__ u,
                        const int* __restrict__ batch,
                        const short* __restrict__ W1T, const short* __restrict__ W2T,
                        const float* __restrict__ b1, const float* __restrict__ b2,
                        float* __restrict__ out) {
    __shared__ short smem[TILE_R * HSTR];  // 33 KB; feat (stride KP) aliases h (stride HSTR)
    __shared__ unsigned offs[TILE_R + 1];  // CSR offsets for the tile
    __shared__ float uvals[TILE_R];        // u[batch[n]] per row
    __shared__ unsigned perms[PCAP];       // staged perm slice (tile-local)

    const int tid = threadIdx.x;
    const int w = tid >> 6;
    const int lane = tid & 63;
    const int row_base = blockIdx.x * TILE_R;

    // ---- stage indirection data ----
    if (tid <= TILE_R) {
        const int n = row_base + tid;
        offs[tid] = (n < N_NODES) ? off[n] : (unsigned)N_EDGES;
    }
    if (tid < TILE_R) {
        const int n = row_base + tid;
        uvals[tid] = (n < N_NODES) ? u[batch[n]] : 0.0f;
    }
    __syncthreads();
    const unsigned s0 = offs[0];
    const int T = (int)(offs[TILE_R] - s0);
    const int Tst = T < PCAP ? T : PCAP;
    for (int j = tid; j < Tst; j += 256) perms[j] = perm[s0 + j];
    __syncthreads();

    // ---- gather: wave w handles 16 nodes; lanes = 4 edge-slots x 16 feat-quads ----
    const int g  = lane >> 4;          // edge slot 0..3
    const int fo = (lane & 15) * 4;    // feature offset (float4)
    const f32x4 z4 = {0.0f, 0.0f, 0.0f, 0.0f};
    const f32x4 ninf4 = {-INFINITY, -INFINITY, -INFINITY, -INFINITY};

#define ACC_LOOP(LD)                                                        \
    {                                                                       \
        int p = es + g;                                                     \
        for (; p + 4 < ee; p += 8) {                                        \
            const int e0 = (int)LD(p);                                      \
            const int e1 = (int)LD(p + 4);                                  \
            const f32x4 v0 = *(const f32x4*)&ea[(size_t)e0 * EO + fo];      \
            const f32x4 v1 = *(const f32x4*)&ea[(size_t)e1 * EO + fo];      \
            sa += v0; ma = max4(ma, v0);                                    \
            sb += v1; mb = max4(mb, v1);                                    \
        }                                                                   \
        if (p < ee) {                                                       \
            const int e0 = (int)LD(p);                                      \
            const f32x4 v0 = *(const f32x4*)&ea[(size_t)e0 * EO + fo];      \
            sa += v0; ma = max4(ma, v0);                                    \
        }                                                                   \
    }
#define LDS_LD(pp) (perms[(pp)])
#define GLB_LD(pp) (perm[s0 + (pp)])

    for (int i = 0; i < 16; ++i) {
        const int rl = w * 16 + i;
        const int n = row_base + rl;
        short* frow = &smem[rl * KP];
        if (n < N_NODES) {
            const int es  = (int)(offs[rl] - s0);
            const int ee  = (int)(offs[rl + 1] - s0);
            const int deg = ee - es;

            f32x4 sa = z4, sb = z4;
            f32x4 ma = ninf4, mb = ninf4;
            if (ee <= PCAP) {
                ACC_LOOP(LDS_LD)
            } else {
                ACC_LOOP(GLB_LD)
            }
            sa += sb; ma = max4(ma, mb);

            // butterfly across the 4 edge slots (xor 16, 32) -> all lanes full
            #pragma unroll
            for (int j = 0; j < 4; ++j) {
                float s = sa[j], m = ma[j];
                s += __shfl_xor(s, 16); m = fmaxf(m, __shfl_xor(m, 16));
                s += __shfl_xor(s, 32); m = fmaxf(m, __shfl_xor(m, 32));
                sa[j] = s; ma[j] = m;
            }

            const float rdeg = 1.0f / fmaxf((float)deg, 1.0f);
            if (g == 0) {
                #pragma unroll
                for (int j = 0; j < 4; ++j) frow[fo + j] = f2bf(sa[j]);
            } else if (g == 1) {
                #pragma unroll
                for (int j = 0; j < 4; ++j)
                    frow[EO + fo + j] = f2bf(deg > 0 ? ma[j] : 0.0f);
            } else if (g == 2) {
                #pragma unroll
                for (int j = 0; j < 4; ++j) frow[2 * EO + fo + j] = f2bf(sa[j] * rdeg);
            } else {
                const int c = (lane & 15) * 2;
                frow[192 + c]     = (c == 0) ? f2bf(uvals[rl]) : (short)0;
                frow[192 + c + 1] = (short)0;
            }
        } else {
            frow[lane] = 0; frow[EO + lane] = 0; frow[2 * EO + lane] = 0;
            if (lane < 32) frow[192 + lane] = 0;
        }
    }
    __syncthreads();

    const int m = lane & 15, q = lane >> 4;
    const f32x4 vzero = {0.0f, 0.0f, 0.0f, 0.0f};

    // ---- GEMM1: 64 x 256, K=224; wave w owns cols [w*64, w*64+64) ----
    f32x4 acc1[4][4];
    #pragma unroll
    for (int a = 0; a < 4; ++a)
        #pragma unroll
        for (int b = 0; b < 4; ++b) acc1[a][b] = vzero;

    for (int kk = 0; kk < 7; ++kk) {
        const int k0 = kk * 32;
        bf16x8 afr[4];
        #pragma unroll
        for (int mt = 0; mt < 4; ++mt)
            afr[mt] = *(const bf16x8*)&smem[(mt * 16 + m) * KP + k0 + q * 8];
        #pragma unroll
        for (int ct = 0; ct < 4; ++ct) {
            const int col = w * 64 + ct * 16 + m;
            bf16x8 bfr = *(const bf16x8*)&W1T[col * KP + k0 + q * 8];
            #pragma unroll
            for (int mt = 0; mt < 4; ++mt)
                acc1[mt][ct] = __builtin_amdgcn_mfma_f32_16x16x32_bf16(afr[mt], bfr, acc1[mt][ct], 0, 0, 0);
        }
    }
    __syncthreads();   // feat fully consumed; smem becomes h

    // epilogue: bias + exact GELU -> h bf16 (stride HSTR)
    #pragma unroll
    for (int ct = 0; ct < 4; ++ct) {
        const int col = w * 64 + ct * 16 + m;
        const float bv = b1[col];
        #pragma unroll
        for (int mt = 0; mt < 4; ++mt) {
            #pragma unroll
            for (int i = 0; i < 4; ++i) {
                float t = acc1[mt][ct][i] + bv;
                t = 0.5f * t * (1.0f + erff(t * 0.70710678118654752f));
                smem[(mt * 16 + q * 4 + i) * HSTR + col] = f2bf(t);
            }
        }
    }
    __syncthreads();

    // ---- GEMM2: 64 x 128, K=256; wave w owns cols [w*32, w*32+32) ----
    f32x4 acc2[4][2];
    #pragma unroll
    for (int a = 0; a < 4; ++a) { acc2[a][0] = vzero; acc2[a][1] = vzero; }

    for (int kk = 0; kk < 8; ++kk) {
        const int k0 = kk * 32;
        bf16x8 afr[4];
        #pragma unroll
        for (int mt = 0; mt < 4; ++mt)
            afr[mt] = *(const bf16x8*)&smem[(mt * 16 + m) * HSTR + k0 + q * 8];
        #pragma unroll
        for (int ct = 0; ct < 2; ++ct) {
            const int col = w * 32 + ct * 16 + m;
            bf16x8 bfr = *(const bf16x8*)&W2T[col * HID + k0 + q * 8];
            #pragma unroll
            for (int mt = 0; mt < 4; ++mt)
                acc2[mt][ct] = __builtin_amdgcn_mfma_f32_16x16x32_bf16(afr[mt], bfr, acc2[mt][ct], 0, 0, 0);
        }
    }

    #pragma unroll
    for (int ct = 0; ct < 2; ++ct) {
        const int col = w * 32 + ct * 16 + m;
        const float bv = b2[col];
        #pragma unroll
        for (int mt = 0; mt < 4; ++mt) {
            #pragma unroll
            for (int i = 0; i < 4; ++i) {
                const int row = row_base + mt * 16 + q * 4 + i;
                if (row < N_NODES) out[(size_t)row * NOUT + col] = acc2[mt][ct][i] + bv;
            }
        }
    }
}

extern "C" void kernel_launch(void* const* d_in, const int* in_sizes, int n_in,
                              void* d_out, int out_size, void* d_ws, size_t ws_size,
                              hipStream_t stream) {
    // inputs: x, edge_index, edge_attr, u, batch, W1, b1, W2, b2
    const int*   ei    = (const int*)d_in[1];
    const float* ea    = (const float*)d_in[2];
    const float* u     = (const float*)d_in[3];
    const int*   batch = (const int*)d_in[4];
    const float* W1    = (const float*)d_in[5];
    const float* b1    = (const float*)d_in[6];
    const float* W2    = (const float*)d_in[7];
    const float* b2    = (const float*)d_in[8];
    float* out = (float*)d_out;

    unsigned* off    = (unsigned*)d_ws;          // N
    unsigned* cursor = off + N_NODES;            // N
    unsigned* perm   = cursor + N_NODES;         // E
    unsigned* bsum   = perm + N_EDGES;           // 512
    unsigned* boff   = bsum + 512;               // 512
    short*    W1T    = (short*)(boff + 512);     // 256*224 bf16
    short*    W2T    = W1T + HID * KP;           // 128*256 bf16

    const int NB = (N_NODES + 255) / 256;        // 391

    hipMemsetAsync(off, 0, (size_t)N_NODES * 4, stream);
    prep_k<<<(HID * KP + NOUT * HID + 255) / 256, 256, 0, stream>>>(W1, W2, W1T, W2T);
    hist_k<<<(N_EDGES + 255) / 256, 256, 0, stream>>>(ei, off);
    scan_part_k<<<NB, 256, 0, stream>>>(off, bsum);
    scan_top_k<<<1, 512, 0, stream>>>(bsum, boff, NB);
    scan_add_k<<<NB, 256, 0, stream>>>(off, boff, cursor);
    place_k<<<(N_EDGES + 255) / 256, 256, 0, stream>>>(ei, cursor, perm);
    fused_k<<<(N_NODES + TILE_R - 1) / TILE_R, 256, 0, stream>>>(
        off, perm, ea, u, batch, W1T, W2T, b1, b2, out);
}

// Round 2
// 671.974 us; speedup vs baseline: 1.1487x; 1.0385x over previous
//
#include <hip/hip_runtime.h>
#include <hip/hip_bf16.h>
#include <math.h>

#define N_NODES 100000
#define N_EDGES 1200000
#define EO      64
#define HID     256
#define NOUT    128
#define KP      224     // 193 padded to 7*32 for K-loop
#define TILE_R  64
#define HSTR    264     // h LDS stride (bf16 elems), padded vs 256
#define PCAP    1280    // staged perm entries per tile (mean ~768); global fallback past this

typedef __attribute__((ext_vector_type(8))) short bf16x8;
typedef __attribute__((ext_vector_type(4))) float f32x4;

__device__ __forceinline__ short f2bf(float x) {
    __hip_bfloat16 h = __float2bfloat16(x);
    return *reinterpret_cast<short*>(&h);
}

__device__ __forceinline__ f32x4 max4(f32x4 a, f32x4 b) {
    f32x4 r;
    r.x = fmaxf(a.x, b.x); r.y = fmaxf(a.y, b.y);
    r.z = fmaxf(a.z, b.z); r.w = fmaxf(a.w, b.w);
    return r;
}

// ---- weight transpose + bf16 convert: W1T[n][k] (k<193 else 0), W2T[n][k] ----
__global__ void prep_k(const float* __restrict__ W1, const float* __restrict__ W2,
                       short* __restrict__ W1T, short* __restrict__ W2T) {
    int i = blockIdx.x * 256 + threadIdx.x;
    if (i < HID * KP) {
        int n = i / KP, k = i - n * KP;
        W1T[i] = (k < 193) ? f2bf(W1[k * HID + n]) : (short)0;
    } else {
        int j = i - HID * KP;
        if (j < NOUT * HID) {
            int n = j / HID, k = j - n * HID;
            W2T[j] = f2bf(W2[k * NOUT + n]);
        }
    }
}

// ---- CSR build ----
__global__ void hist_k(const int* __restrict__ ei, unsigned* __restrict__ hist) {
    int e4 = (blockIdx.x * 256 + threadIdx.x) * 4;
    if (e4 < N_EDGES) {
        const int4 c = *(const int4*)&ei[N_EDGES + e4];
        atomicAdd(&hist[c.x], 1u);
        atomicAdd(&hist[c.y], 1u);
        atomicAdd(&hist[c.z], 1u);
        atomicAdd(&hist[c.w], 1u);
    }
}

__global__ void scan_part_k(unsigned* __restrict__ off, unsigned* __restrict__ bsum) {
    __shared__ unsigned s[256];
    int t = threadIdx.x, i = blockIdx.x * 256 + t;
    unsigned v = (i < N_NODES) ? off[i] : 0u;
    s[t] = v; __syncthreads();
    for (int d = 1; d < 256; d <<= 1) {
        unsigned x = (t >= d) ? s[t - d] : 0u; __syncthreads();
        s[t] += x; __syncthreads();
    }
    if (i < N_NODES) off[i] = s[t] - v;       // block-local exclusive
    if (t == 255) bsum[blockIdx.x] = s[255];
}

__global__ void scan_top_k(const unsigned* __restrict__ bsum, unsigned* __restrict__ boff, int nb) {
    __shared__ unsigned s[512];
    int t = threadIdx.x;
    unsigned v = (t < nb) ? bsum[t] : 0u;
    s[t] = v; __syncthreads();
    for (int d = 1; d < 512; d <<= 1) {
        unsigned x = (t >= d) ? s[t - d] : 0u; __syncthreads();
        s[t] += x; __syncthreads();
    }
    boff[t] = s[t] - v;
}

__global__ void scan_add_k(unsigned* __restrict__ off, const unsigned* __restrict__ boff,
                           unsigned* __restrict__ cursor) {
    int i = blockIdx.x * 256 + threadIdx.x;
    if (i < N_NODES) {
        unsigned o = off[i] + boff[blockIdx.x];
        off[i] = o; cursor[i] = o;
    }
}

__global__ void place_k(const int* __restrict__ ei, unsigned* __restrict__ cursor,
                        unsigned* __restrict__ perm) {
    int e4 = (blockIdx.x * 256 + threadIdx.x) * 4;
    if (e4 < N_EDGES) {
        const int4 c = *(const int4*)&ei[N_EDGES + e4];
        unsigned p0 = atomicAdd(&cursor[c.x], 1u); perm[p0] = (unsigned)(e4);
        unsigned p1 = atomicAdd(&cursor[c.y], 1u); perm[p1] = (unsigned)(e4 + 1);
        unsigned p2 = atomicAdd(&cursor[c.z], 1u); perm[p2] = (unsigned)(e4 + 2);
        unsigned p3 = atomicAdd(&cursor[c.w], 1u); perm[p3] = (unsigned)(e4 + 3);
    }
}

// ---- fused gather + MLP (bf16 MFMA, fp32 accum) ----
// Gather structure: wave w owns 16 rows; 4 CONCURRENT nodes per wave
// (16-lane group per node), each lane accumulating one f32x4 chunk over all
// of its node's edges with 4 independent accumulator pairs. This cuts the
// serial dependent rounds per wave from 16 to 4 and removes all shuffles.
// Indirection (off/perm/u[batch]) is LDS-staged so ea addresses come from lgkm.
__launch_bounds__(256)
__global__ void fused_k(const unsigned* __restrict__ off, const unsigned* __restrict__ perm,
                        const float* __restrict__ ea, const float* __restrict__ u,
                        const int* __restrict__ batch,
                        const short* __restrict__ W1T, const short* __restrict__ W2T,
                        const float* __restrict__ b1, const float* __restrict__ b2,
                        float* __restrict__ out) {
    __shared__ short smem[TILE_R * HSTR];  // 33 KB; feat (stride KP) aliases h (stride HSTR)
    __shared__ unsigned offs[TILE_R + 1];  // CSR offsets for the tile
    __shared__ float uvals[TILE_R];        // u[batch[n]] per row
    __shared__ unsigned perms[PCAP];       // staged perm slice (tile-local)

    const int tid = threadIdx.x;
    const int w = tid >> 6;
    const int lane = tid & 63;
    const int row_base = blockIdx.x * TILE_R;

    // ---- stage indirection data ----
    if (tid <= TILE_R) {
        const int n = row_base + tid;
        offs[tid] = (n < N_NODES) ? off[n] : (unsigned)N_EDGES;
    }
    if (tid < TILE_R) {
        const int n = row_base + tid;
        uvals[tid] = (n < N_NODES) ? u[batch[n]] : 0.0f;
    }
    __syncthreads();
    const unsigned s0 = offs[0];
    const int T = (int)(offs[TILE_R] - s0);
    const int Tst = T < PCAP ? T : PCAP;
    for (int j = tid; j < Tst; j += 256) perms[j] = perm[s0 + j];
    __syncthreads();

    // ---- gather ----
    const int g16 = lane >> 4;         // which of 4 concurrent nodes
    const int fo  = (lane & 15) * 4;   // feature float4 offset within the row
    const f32x4 z4 = {0.0f, 0.0f, 0.0f, 0.0f};
    const f32x4 ninf4 = {-INFINITY, -INFINITY, -INFINITY, -INFINITY};

#define GATHER_LOOP(LD)                                                     \
    {                                                                       \
        int p = es;                                                         \
        for (; p + 3 < ee; p += 4) {                                        \
            const int e0 = (int)LD(p);                                      \
            const int e1 = (int)LD(p + 1);                                  \
            const int e2 = (int)LD(p + 2);                                  \
            const int e3 = (int)LD(p + 3);                                  \
            const f32x4 v0 = *(const f32x4*)&ea[(size_t)e0 * EO + fo];      \
            const f32x4 v1 = *(const f32x4*)&ea[(size_t)e1 * EO + fo];      \
            const f32x4 v2 = *(const f32x4*)&ea[(size_t)e2 * EO + fo];      \
            const f32x4 v3 = *(const f32x4*)&ea[(size_t)e3 * EO + fo];      \
            sv0 += v0; mv0 = max4(mv0, v0);                                 \
            sv1 += v1; mv1 = max4(mv1, v1);                                 \
            sv2 += v2; mv2 = max4(mv2, v2);                                 \
            sv3 += v3; mv3 = max4(mv3, v3);                                 \
        }                                                                   \
        for (; p < ee; ++p) {                                               \
            const int e0 = (int)LD(p);                                      \
            const f32x4 v0 = *(const f32x4*)&ea[(size_t)e0 * EO + fo];      \
            sv0 += v0; mv0 = max4(mv0, v0);                                 \
        }                                                                   \
    }
#define LDS_LD(pp) (perms[(pp)])
#define GLB_LD(pp) (perm[s0 + (pp)])

    for (int i = 0; i < 4; ++i) {
        const int rl = w * 16 + i * 4 + g16;
        const int es = (int)(offs[rl] - s0);
        const int ee = (int)(offs[rl + 1] - s0);
        const int deg = ee - es;

        f32x4 sv0 = z4, sv1 = z4, sv2 = z4, sv3 = z4;
        f32x4 mv0 = ninf4, mv1 = ninf4, mv2 = ninf4, mv3 = ninf4;
        if (ee <= PCAP) {
            GATHER_LOOP(LDS_LD)
        } else {
            GATHER_LOOP(GLB_LD)
        }
        const f32x4 sv = (sv0 + sv1) + (sv2 + sv3);
        const f32x4 mv = max4(max4(mv0, mv1), max4(mv2, mv3));
        const float rdeg = 1.0f / fmaxf((float)deg, 1.0f);

        short* frow = &smem[rl * KP];
        #pragma unroll
        for (int j = 0; j < 4; ++j) {
            frow[fo + j]          = f2bf(sv[j]);
            frow[EO + fo + j]     = f2bf(deg > 0 ? mv[j] : 0.0f);
            frow[2 * EO + fo + j] = f2bf(sv[j] * rdeg);
        }
    }

    // tail cols 192..223: u then zero-pad (all rows, incl. out-of-range)
    {
        const int rl = w * 16 + (lane & 15);
        short* frow = &smem[rl * KP];
        const int c0 = 192 + g16 * 8;
        #pragma unroll
        for (int j = 0; j < 8; ++j)
            frow[c0 + j] = (c0 + j == 192) ? f2bf(uvals[rl]) : (short)0;
    }
    __syncthreads();

    const int m = lane & 15, q = lane >> 4;
    const f32x4 vzero = {0.0f, 0.0f, 0.0f, 0.0f};

    // ---- GEMM1: 64 x 256, K=224; wave w owns cols [w*64, w*64+64) ----
    f32x4 acc1[4][4];
    #pragma unroll
    for (int a = 0; a < 4; ++a)
        #pragma unroll
        for (int b = 0; b < 4; ++b) acc1[a][b] = vzero;

    for (int kk = 0; kk < 7; ++kk) {
        const int k0 = kk * 32;
        bf16x8 afr[4];
        #pragma unroll
        for (int mt = 0; mt < 4; ++mt)
            afr[mt] = *(const bf16x8*)&smem[(mt * 16 + m) * KP + k0 + q * 8];
        #pragma unroll
        for (int ct = 0; ct < 4; ++ct) {
            const int col = w * 64 + ct * 16 + m;
            bf16x8 bfr = *(const bf16x8*)&W1T[col * KP + k0 + q * 8];
            #pragma unroll
            for (int mt = 0; mt < 4; ++mt)
                acc1[mt][ct] = __builtin_amdgcn_mfma_f32_16x16x32_bf16(afr[mt], bfr, acc1[mt][ct], 0, 0, 0);
        }
    }
    __syncthreads();   // feat fully consumed; smem becomes h

    // epilogue: bias + exact GELU -> h bf16 (stride HSTR)
    #pragma unroll
    for (int ct = 0; ct < 4; ++ct) {
        const int col = w * 64 + ct * 16 + m;
        const float bv = b1[col];
        #pragma unroll
        for (int mt = 0; mt < 4; ++mt) {
            #pragma unroll
            for (int i = 0; i < 4; ++i) {
                float t = acc1[mt][ct][i] + bv;
                t = 0.5f * t * (1.0f + erff(t * 0.70710678118654752f));
                smem[(mt * 16 + q * 4 + i) * HSTR + col] = f2bf(t);
            }
        }
    }
    __syncthreads();

    // ---- GEMM2: 64 x 128, K=256; wave w owns cols [w*32, w*32+32) ----
    f32x4 acc2[4][2];
    #pragma unroll
    for (int a = 0; a < 4; ++a) { acc2[a][0] = vzero; acc2[a][1] = vzero; }

    for (int kk = 0; kk < 8; ++kk) {
        const int k0 = kk * 32;
        bf16x8 afr[4];
        #pragma unroll
        for (int mt = 0; mt < 4; ++mt)
            afr[mt] = *(const bf16x8*)&smem[(mt * 16 + m) * HSTR + k0 + q * 8];
        #pragma unroll
        for (int ct = 0; ct < 2; ++ct) {
            const int col = w * 32 + ct * 16 + m;
            bf16x8 bfr = *(const bf16x8*)&W2T[col * HID + k0 + q * 8];
            #pragma unroll
            for (int mt = 0; mt < 4; ++mt)
                acc2[mt][ct] = __builtin_amdgcn_mfma_f32_16x16x32_bf16(afr[mt], bfr, acc2[mt][ct], 0, 0, 0);
        }
    }

    #pragma unroll
    for (int ct = 0; ct < 2; ++ct) {
        const int col = w * 32 + ct * 16 + m;
        const float bv = b2[col];
        #pragma unroll
        for (int mt = 0; mt < 4; ++mt) {
            #pragma unroll
            for (int i = 0; i < 4; ++i) {
                const int row = row_base + mt * 16 + q * 4 + i;
                if (row < N_NODES) out[(size_t)row * NOUT + col] = acc2[mt][ct][i] + bv;
            }
        }
    }
}

extern "C" void kernel_launch(void* const* d_in, const int* in_sizes, int n_in,
                              void* d_out, int out_size, void* d_ws, size_t ws_size,
                              hipStream_t stream) {
    // inputs: x, edge_index, edge_attr, u, batch, W1, b1, W2, b2
    const int*   ei    = (const int*)d_in[1];
    const float* ea    = (const float*)d_in[2];
    const float* u     = (const float*)d_in[3];
    const int*   batch = (const int*)d_in[4];
    const float* W1    = (const float*)d_in[5];
    const float* b1    = (const float*)d_in[6];
    const float* W2    = (const float*)d_in[7];
    const float* b2    = (const float*)d_in[8];
    float* out = (float*)d_out;

    unsigned* off    = (unsigned*)d_ws;          // N
    unsigned* cursor = off + N_NODES;            // N
    unsigned* perm   = cursor + N_NODES;         // E
    unsigned* bsum   = perm + N_EDGES;           // 512
    unsigned* boff   = bsum + 512;               // 512
    short*    W1T    = (short*)(boff + 512);     // 256*224 bf16
    short*    W2T    = W1T + HID * KP;           // 128*256 bf16

    const int NB = (N_NODES + 255) / 256;        // 391

    hipMemsetAsync(off, 0, (size_t)N_NODES * 4, stream);
    prep_k<<<(HID * KP + NOUT * HID + 255) / 256, 256, 0, stream>>>(W1, W2, W1T, W2T);
    hist_k<<<(N_EDGES / 4 + 255) / 256, 256, 0, stream>>>(ei, off);
    scan_part_k<<<NB, 256, 0, stream>>>(off, bsum);
    scan_top_k<<<1, 512, 0, stream>>>(bsum, boff, NB);
    scan_add_k<<<NB, 256, 0, stream>>>(off, boff, cursor);
    place_k<<<(N_EDGES / 4 + 255) / 256, 256, 0, stream>>>(ei, cursor, perm);
    fused_k<<<(N_NODES + TILE_R - 1) / TILE_R, 256, 0, stream>>>(
        off, perm, ea, u, batch, W1T, W2T, b1, b2, out);
}